// Round 6
// baseline (421.514 us; speedup 1.0000x reference)
//
#include <hip/hip_runtime.h>

#define B_ 256
#define T_ 512
#define N_ 128

typedef float  f32x4 __attribute__((ext_vector_type(4)));
typedef short  s16x8 __attribute__((ext_vector_type(8)));
typedef unsigned int u32x4 __attribute__((ext_vector_type(4)));

__device__ __forceinline__ float readlane_f(float v, int k) {
    return __int_as_float(__builtin_amdgcn_readlane(__float_as_int(v), k));
}
// bf16 truncation pack: lo -> low 16, hi -> high 16
__device__ __forceinline__ unsigned int pack_trunc(float lo, float hi) {
    return (__float_as_uint(hi) & 0xFFFF0000u) | (__float_as_uint(lo) >> 16);
}
// round-to-nearest-even f32 -> bf16 (prologue only)
__device__ __forceinline__ unsigned int bf16_rne(float f) {
    unsigned int u = __float_as_uint(f);
    u += 0x7FFFu + ((u >> 16) & 1u);
    return u >> 16;
}

// ONE WAVE per chain (256 blocks x 64 threads). No barriers, no readlane
// broadcasts on the chain. Identity split: e^T = 1 + Delta, so
//   alpha_new[j] = e^{E[j]} * ( S + sum_k alpha[k]*Delta[k][j] ),
// with S = sum_k alpha[k] exact in f32 and the small correction (|Delta|<=0.05,
// ~1e-3 of the total) via bf16 MFMA: 8 j-tiles x 4 k-tiles of
// mfma_f32_16x16x32_bf16. Delta fragments (32 x s16x8 = 128 VGPRs) resident.
// A-operand is ROW-REPLICATED (all lane-groups read the same 8 alphas from
// LDS), making the result independent of A's row<->lane mapping; every D reg
// of every lane then holds y[16*jt + (lane&15)] (col mapping per m89).
// Per step: 8 ds_read_b128 (broadcast) -> 16 pack -> 32 MFMA -> eltwise ->
// 8 ds_write_b32 -> S-reduce. Same-wave LDS ordering via lgkmcnt only.
__global__ __launch_bounds__(64, 1) void crf_fused_kernel(
    const float* __restrict__ lp,      // [B,T,N]
    const float* __restrict__ trans,   // [N,N]
    const float* __restrict__ startt,  // [N]
    const float* __restrict__ endt,    // [N]
    const int*   __restrict__ target,  // [B,T]
    const int*   __restrict__ lengths, // [B]
    float*       __restrict__ out)     // [B]
{
    const int b = blockIdx.x;
    const int l = threadIdx.x;          // 0..63
    const int c = l & 15;               // column within a 16-wide j-tile
    const int g = l >> 4;               // k-slot group (0..3)

    __shared__ float xld[N_];           // alpha in j-order (512 B)

    const float* lpb = lp + (size_t)b * (T_ * N_);
    const int len = lengths[b];         // in [256, 512]

    // ---- Delta fragments: Bf[kt][jt], lane holds Delta[32kt+8g+i][16jt+c] ----
    s16x8 Bf[4][8];
    #pragma unroll
    for (int kt = 0; kt < 4; ++kt) {
        #pragma unroll
        for (int jt = 0; jt < 8; ++jt) {
            const float* tq = trans + (32 * kt + 8 * g) * N_ + 16 * jt + c;
            unsigned int d0, d1, d2, d3;
            d0 = bf16_rne(expm1f(tq[0 * N_])) | (bf16_rne(expm1f(tq[1 * N_])) << 16);
            d1 = bf16_rne(expm1f(tq[2 * N_])) | (bf16_rne(expm1f(tq[3 * N_])) << 16);
            d2 = bf16_rne(expm1f(tq[4 * N_])) | (bf16_rne(expm1f(tq[5 * N_])) << 16);
            d3 = bf16_rne(expm1f(tq[6 * N_])) | (bf16_rne(expm1f(tq[7 * N_])) << 16);
            u32x4 u = { d0, d1, d2, d3 };
            Bf[kt][jt] = __builtin_bit_cast(s16x8, u);
        }
    }

    // ---- t = 0 alpha in j-layout: a[r] = alpha[16r + c], replicated x4 ----
    float a[8];
    #pragma unroll
    for (int r = 0; r < 8; ++r)
        a[r] = __expf(startt[16 * r + c] + lpb[16 * r + c]);

    #pragma unroll
    for (int r = 0; r < 8; ++r) xld[16 * r + c] = a[r];

    float S = 0.f;
    #pragma unroll
    for (int r = 0; r < 8; ++r) S += a[r];
    S += __shfl_xor(S, 1); S += __shfl_xor(S, 2);
    S += __shfl_xor(S, 4); S += __shfl_xor(S, 8);

    int Mexp = 0;                       // exact power-of-2 rescale accumulator

    // emission prefetch, distance 2 (len >= 256, rows 1..2 valid)
    float cur[8], nxt[8];
    #pragma unroll
    for (int r = 0; r < 8; ++r) {
        cur[r] = lpb[1 * N_ + 16 * r + c];
        nxt[r] = lpb[2 * N_ + 16 * r + c];
    }

    for (int t = 1; t < len; ++t) {
        const int tp2 = min(t + 2, T_ - 1);      // clamp: always in-bounds
        float nn[8];
        #pragma unroll
        for (int r = 0; r < 8; ++r) nn[r] = lpb[tp2 * N_ + 16 * r + c];

        float eexp[8];
        #pragma unroll
        for (int r = 0; r < 8; ++r) eexp[r] = __expf(cur[r]);

        // A fragments: broadcast-read alpha (written end of prev iter),
        // row-replicated, truncation-pack to bf16
        s16x8 Af[4];
        #pragma unroll
        for (int kt = 0; kt < 4; ++kt) {
            const f32x4* ls = (const f32x4*)&xld[32 * kt + 8 * g];
            f32x4 lo = ls[0], hi = ls[1];
            u32x4 u = { pack_trunc(lo[0], lo[1]), pack_trunc(lo[2], lo[3]),
                        pack_trunc(hi[0], hi[1]), pack_trunc(hi[2], hi[3]) };
            Af[kt] = __builtin_bit_cast(s16x8, u);
        }

        // correction y[j] = sum_k alpha_bf16[k] * Delta[k][j]
        float y[8];
        #pragma unroll
        for (int jt = 0; jt < 8; ++jt) {
            f32x4 acc = { 0.f, 0.f, 0.f, 0.f };
            #pragma unroll
            for (int kt = 0; kt < 4; ++kt)
                acc = __builtin_amdgcn_mfma_f32_16x16x32_bf16(
                          Af[kt], Bf[kt][jt], acc, 0, 0, 0);
            y[jt] = acc[0];
        }

        #pragma unroll
        for (int r = 0; r < 8; ++r) a[r] = (S + y[r]) * eexp[r];

        if ((t & 3) == 0) {             // exact pow2 rescale, wave-uniform
            float v = readlane_f(a[0], 0);
            unsigned int eb = (__float_as_uint(v) >> 23) & 0xFFu;
            float isc = __uint_as_float((254u - eb) << 23);
            #pragma unroll
            for (int r = 0; r < 8; ++r) a[r] *= isc;
            Mexp += (int)eb - 127;
        }

        #pragma unroll
        for (int r = 0; r < 8; ++r) xld[16 * r + c] = a[r];

        float Sn = 0.f;
        #pragma unroll
        for (int r = 0; r < 8; ++r) Sn += a[r];
        Sn += __shfl_xor(Sn, 1); Sn += __shfl_xor(Sn, 2);
        Sn += __shfl_xor(Sn, 4); Sn += __shfl_xor(Sn, 8);
        S = Sn;

        #pragma unroll
        for (int r = 0; r < 8; ++r) { cur[r] = nxt[r]; nxt[r] = nn[r]; }
    }

    // ---- log Z (values replicated across the 4 lane-groups) ----
    float f = 0.f;
    #pragma unroll
    for (int r = 0; r < 8; ++r) f += a[r] * __expf(endt[16 * r + c]);
    f += __shfl_xor(f, 1); f += __shfl_xor(f, 2);
    f += __shfl_xor(f, 4); f += __shfl_xor(f, 8);
    const float logZ = (float)Mexp * 0.69314718055994531f + __logf(f);

    // ---- path score (gathers) ----
    const int* tg = target + b * T_;
    float acc2 = 0.f;
    for (int t = l; t < len; t += 64) {
        int cc = tg[t];
        acc2 += lpb[t * N_ + cc];
        if (t + 1 < len) acc2 += trans[cc * N_ + tg[t + 1]];
    }
    #pragma unroll
    for (int off = 32; off > 0; off >>= 1) acc2 += __shfl_xor(acc2, off);

    if (l == 0) out[b] = acc2 + startt[tg[0]] + endt[tg[len - 1]] - logZ;
}

extern "C" void kernel_launch(void* const* d_in, const int* in_sizes, int n_in,
                              void* d_out, int out_size, void* d_ws, size_t ws_size,
                              hipStream_t stream) {
    const float* lp     = (const float*)d_in[0];
    const float* trans  = (const float*)d_in[1];
    const float* st     = (const float*)d_in[2];
    const float* en     = (const float*)d_in[3];
    const int*   target = (const int*)d_in[4];
    const int*   lens   = (const int*)d_in[5];
    float* out = (float*)d_out;

    crf_fused_kernel<<<B_, 64, 0, stream>>>(lp, trans, st, en, target, lens, out);
}

// Round 7
// 385.419 us; speedup vs baseline: 1.0937x; 1.0937x over previous
//
#include <hip/hip_runtime.h>

#define B_ 256
#define T_ 512
#define N_ 128

typedef float  f32x4 __attribute__((ext_vector_type(4)));
typedef short  s16x8 __attribute__((ext_vector_type(8)));
typedef unsigned int u32x4 __attribute__((ext_vector_type(4)));

__device__ __forceinline__ float readlane_f(float v, int k) {
    return __int_as_float(__builtin_amdgcn_readlane(__float_as_int(v), k));
}
// round-to-nearest-even f32 -> bf16 (prologue only)
__device__ __forceinline__ unsigned int bf16_rne(float f) {
    unsigned int u = __float_as_uint(f);
    u += 0x7FFFu + ((u >> 16) & 1u);
    return u >> 16;
}
// ONE v_perm_b32: D = (hi.bf16_trunc << 16) | lo.bf16_trunc
__device__ __forceinline__ unsigned int pack_bf16(float lo, float hi) {
    return __builtin_amdgcn_perm(__float_as_uint(hi), __float_as_uint(lo),
                                 0x07060302u);
}

// ONE WAVE per chain (256 blocks x 64 threads). No barriers anywhere.
// Identity split (verified R6, absmax 0): e^T = 1 + Delta,
//   alpha_new[j] = e^{E[j]} * ( S + sum_k alpha[k]*Delta[k][j] ),
// S exact in f32, correction via bf16 MFMA (8 j-tiles x [2+2] k-tiles).
// R7 chain cuts vs R6:
//  - S computed FROM the fragment ds_read_b128s (31-add tree + 2 shfl_xor),
//    overlapped with the MFMA path (was: 4-deep shfl chain at end of step)
//  - bf16 pack via single v_perm_b32 (was: 3 VALU per u32)
//  - MFMA per j-tile: two independent 2-deep chains + add (was: 4-deep)
__global__ __launch_bounds__(64, 1) void crf_fused_kernel(
    const float* __restrict__ lp,      // [B,T,N]
    const float* __restrict__ trans,   // [N,N]
    const float* __restrict__ startt,  // [N]
    const float* __restrict__ endt,    // [N]
    const int*   __restrict__ target,  // [B,T]
    const int*   __restrict__ lengths, // [B]
    float*       __restrict__ out)     // [B]
{
    const int b = blockIdx.x;
    const int l = threadIdx.x;          // 0..63
    const int c = l & 15;               // column within a 16-wide j-tile
    const int g = l >> 4;               // k-slot group (0..3)

    __shared__ float xld[N_];           // alpha in j-order (512 B)

    const float* lpb = lp + (size_t)b * (T_ * N_);
    const int len = lengths[b];         // in [256, 512]

    // ---- Delta fragments: Bf[kt][jt], lane holds Delta[32kt+8g+i][16jt+c] ----
    s16x8 Bf[4][8];
    #pragma unroll
    for (int kt = 0; kt < 4; ++kt) {
        #pragma unroll
        for (int jt = 0; jt < 8; ++jt) {
            const float* tq = trans + (32 * kt + 8 * g) * N_ + 16 * jt + c;
            unsigned int d0, d1, d2, d3;
            d0 = bf16_rne(expm1f(tq[0 * N_])) | (bf16_rne(expm1f(tq[1 * N_])) << 16);
            d1 = bf16_rne(expm1f(tq[2 * N_])) | (bf16_rne(expm1f(tq[3 * N_])) << 16);
            d2 = bf16_rne(expm1f(tq[4 * N_])) | (bf16_rne(expm1f(tq[5 * N_])) << 16);
            d3 = bf16_rne(expm1f(tq[6 * N_])) | (bf16_rne(expm1f(tq[7 * N_])) << 16);
            u32x4 u = { d0, d1, d2, d3 };
            Bf[kt][jt] = __builtin_bit_cast(s16x8, u);
        }
    }

    // ---- t = 0 alpha in j-layout: a[r] = alpha[16r + c], replicated x4 ----
    float a[8];
    #pragma unroll
    for (int r = 0; r < 8; ++r)
        a[r] = __expf(startt[16 * r + c] + lpb[16 * r + c]);

    #pragma unroll
    for (int r = 0; r < 8; ++r) xld[16 * r + c] = a[r];

    int Mexp = 0;                       // exact power-of-2 rescale accumulator

    // emission prefetch, distance 2 (len >= 256, rows 1..2 valid)
    float cur[8], nxt[8];
    #pragma unroll
    for (int r = 0; r < 8; ++r) {
        cur[r] = lpb[1 * N_ + 16 * r + c];
        nxt[r] = lpb[2 * N_ + 16 * r + c];
    }

    for (int t = 1; t < len; ++t) {
        const int tp2 = min(t + 2, T_ - 1);      // clamp: always in-bounds
        float nn[8];
        #pragma unroll
        for (int r = 0; r < 8; ++r) nn[r] = lpb[tp2 * N_ + 16 * r + c];

        float eexp[8];
        #pragma unroll
        for (int r = 0; r < 8; ++r) eexp[r] = __expf(cur[r]);

        // ---- fragment loads: 8 x ds_read_b128 (broadcast, conflict-free) ----
        f32x4 lo[4], hi[4];
        #pragma unroll
        for (int kt = 0; kt < 4; ++kt) {
            const f32x4* ls = (const f32x4*)&xld[32 * kt + 8 * g];
            lo[kt] = ls[0];
            hi[kt] = ls[1];
        }

        // ---- S from the SAME loads: 31-add tree + 2 shfls (off MFMA path) ----
        f32x4 sv = ((lo[0] + hi[0]) + (lo[1] + hi[1]))
                 + ((lo[2] + hi[2]) + (lo[3] + hi[3]));
        float S = (sv[0] + sv[1]) + (sv[2] + sv[3]);
        S += __shfl_xor(S, 16);
        S += __shfl_xor(S, 32);

        // ---- pack A fragments: 16 x v_perm_b32 ----
        s16x8 Af[4];
        #pragma unroll
        for (int kt = 0; kt < 4; ++kt) {
            u32x4 u = { pack_bf16(lo[kt][0], lo[kt][1]),
                        pack_bf16(lo[kt][2], lo[kt][3]),
                        pack_bf16(hi[kt][0], hi[kt][1]),
                        pack_bf16(hi[kt][2], hi[kt][3]) };
            Af[kt] = __builtin_bit_cast(s16x8, u);
        }

        // ---- correction y: per jt two independent 2-deep MFMA chains ----
        float y[8];
        #pragma unroll
        for (int jt = 0; jt < 8; ++jt) {
            f32x4 p = { 0.f, 0.f, 0.f, 0.f };
            f32x4 q = { 0.f, 0.f, 0.f, 0.f };
            p = __builtin_amdgcn_mfma_f32_16x16x32_bf16(Af[0], Bf[0][jt], p, 0, 0, 0);
            q = __builtin_amdgcn_mfma_f32_16x16x32_bf16(Af[2], Bf[2][jt], q, 0, 0, 0);
            p = __builtin_amdgcn_mfma_f32_16x16x32_bf16(Af[1], Bf[1][jt], p, 0, 0, 0);
            q = __builtin_amdgcn_mfma_f32_16x16x32_bf16(Af[3], Bf[3][jt], q, 0, 0, 0);
            y[jt] = p[0] + q[0];
        }

        #pragma unroll
        for (int r = 0; r < 8; ++r) a[r] = (S + y[r]) * eexp[r];

        if ((t & 3) == 0) {             // exact pow2 rescale, wave-uniform
            float v = readlane_f(a[0], 0);
            unsigned int eb = (__float_as_uint(v) >> 23) & 0xFFu;
            float isc = __uint_as_float((254u - eb) << 23);
            #pragma unroll
            for (int r = 0; r < 8; ++r) a[r] *= isc;
            Mexp += (int)eb - 127;
        }

        #pragma unroll
        for (int r = 0; r < 8; ++r) xld[16 * r + c] = a[r];

        #pragma unroll
        for (int r = 0; r < 8; ++r) { cur[r] = nxt[r]; nxt[r] = nn[r]; }
    }

    // ---- log Z (values replicated across the 4 lane-groups) ----
    float f = 0.f;
    #pragma unroll
    for (int r = 0; r < 8; ++r) f += a[r] * __expf(endt[16 * r + c]);
    f += __shfl_xor(f, 1); f += __shfl_xor(f, 2);
    f += __shfl_xor(f, 4); f += __shfl_xor(f, 8);
    const float logZ = (float)Mexp * 0.69314718055994531f + __logf(f);

    // ---- path score (gathers) ----
    const int* tg = target + b * T_;
    float acc2 = 0.f;
    for (int t = l; t < len; t += 64) {
        int cc = tg[t];
        acc2 += lpb[t * N_ + cc];
        if (t + 1 < len) acc2 += trans[cc * N_ + tg[t + 1]];
    }
    #pragma unroll
    for (int off = 32; off > 0; off >>= 1) acc2 += __shfl_xor(acc2, off);

    if (l == 0) out[b] = acc2 + startt[tg[0]] + endt[tg[len - 1]] - logZ;
}

extern "C" void kernel_launch(void* const* d_in, const int* in_sizes, int n_in,
                              void* d_out, int out_size, void* d_ws, size_t ws_size,
                              hipStream_t stream) {
    const float* lp     = (const float*)d_in[0];
    const float* trans  = (const float*)d_in[1];
    const float* st     = (const float*)d_in[2];
    const float* en     = (const float*)d_in[3];
    const int*   target = (const int*)d_in[4];
    const int*   lens   = (const int*)d_in[5];
    float* out = (float*)d_out;

    crf_fused_kernel<<<B_, 64, 0, stream>>>(lp, trans, st, en, target, lens, out);
}

// Round 9
// 358.782 us; speedup vs baseline: 1.1748x; 1.0742x over previous
//
#include <hip/hip_runtime.h>

#define B_ 256
#define T_ 512
#define N_ 128

typedef float  f32x4 __attribute__((ext_vector_type(4)));
typedef short  s16x8 __attribute__((ext_vector_type(8)));
typedef unsigned int u32x4 __attribute__((ext_vector_type(4)));

__device__ __forceinline__ float readlane_f(float v, int k) {
    return __int_as_float(__builtin_amdgcn_readlane(__float_as_int(v), k));
}
// round-to-nearest-even f32 -> bf16 (prologue only)
__device__ __forceinline__ unsigned int bf16_rne(float f) {
    unsigned int u = __float_as_uint(f);
    u += 0x7FFFu + ((u >> 16) & 1u);
    return u >> 16;
}
// ONE v_perm_b32: D = (hi.bf16_trunc << 16) | lo.bf16_trunc
__device__ __forceinline__ unsigned int pack_bf16(float lo, float hi) {
    return __builtin_amdgcn_perm(__float_as_uint(hi), __float_as_uint(lo),
                                 0x07060302u);
}
// one DPP-paired add stage: x + dpp_move(x). VALU-speed cross-lane (<=16).
// ctrl must be a compile-time constant -> template parameter.
template <int CTRL>
__device__ __forceinline__ float dpp_add(float x) {
    int m = __builtin_amdgcn_update_dpp(0, __float_as_int(x), CTRL, 0xF, 0xF, true);
    return x + __int_as_float(m);
}
// full 16-lane sum reduction (values replicated per 16-lane group after it)
__device__ __forceinline__ float dpp_sum16(float s8) {
    s8 = dpp_add<0xB1>(s8);     // quad_perm [1,0,3,2]  (xor 1)
    s8 = dpp_add<0x4E>(s8);     // quad_perm [2,3,0,1]  (xor 2)
    s8 = dpp_add<0x141>(s8);    // row_half_mirror      (pairs quads)
    s8 = dpp_add<0x140>(s8);    // row_mirror           (pairs octets)
    return s8;
}

// ONE WAVE per chain (256 blocks x 64 threads). No barriers anywhere.
// Identity split (verified R6/R7, absmax 0): e^T = 1 + Delta,
//   alpha_new[j] = e^{E[j]} * ( S + sum_k alpha[k]*Delta[k][j] ),
// S exact in f32, correction via bf16 MFMA (8 j-tiles x [2+2] k-tiles).
// R8 changes vs R7 (both target chain latency, not instruction count):
//  - UNROLL-2 with two named emission register sets (emA odd steps, emB even
//    steps), refilled inside the step right after consumption: no rotation
//    movs -> no per-iteration vmcnt(0) drain; ~2-step (~1100 cy) slack per
//    load batch. (R7 exposed ~900 cy/step of global-load latency.)
//  - S computed from a[] registers via 4 DPP add stages right after a[] is
//    produced: overlaps the LDS round-trip, removes 2 DS-pipe shuffles from
//    the chain tail.
__global__ __launch_bounds__(64, 1) void crf_fused_kernel(
    const float* __restrict__ lp,      // [B,T,N]
    const float* __restrict__ trans,   // [N,N]
    const float* __restrict__ startt,  // [N]
    const float* __restrict__ endt,    // [N]
    const int*   __restrict__ target,  // [B,T]
    const int*   __restrict__ lengths, // [B]
    float*       __restrict__ out)     // [B]
{
    const int b = blockIdx.x;
    const int l = threadIdx.x;          // 0..63
    const int c = l & 15;               // column within a 16-wide j-tile
    const int g = l >> 4;               // k-slot group (0..3)

    __shared__ float xld[N_];           // alpha in j-order (512 B)

    const float* lpb = lp + (size_t)b * (T_ * N_);
    const int len = lengths[b];         // in [256, 512]

    // ---- Delta fragments: Bf[kt][jt], lane holds Delta[32kt+8g+i][16jt+c] ----
    s16x8 Bf[4][8];
    #pragma unroll
    for (int kt = 0; kt < 4; ++kt) {
        #pragma unroll
        for (int jt = 0; jt < 8; ++jt) {
            const float* tq = trans + (32 * kt + 8 * g) * N_ + 16 * jt + c;
            unsigned int d0, d1, d2, d3;
            d0 = bf16_rne(expm1f(tq[0 * N_])) | (bf16_rne(expm1f(tq[1 * N_])) << 16);
            d1 = bf16_rne(expm1f(tq[2 * N_])) | (bf16_rne(expm1f(tq[3 * N_])) << 16);
            d2 = bf16_rne(expm1f(tq[4 * N_])) | (bf16_rne(expm1f(tq[5 * N_])) << 16);
            d3 = bf16_rne(expm1f(tq[6 * N_])) | (bf16_rne(expm1f(tq[7 * N_])) << 16);
            u32x4 u = { d0, d1, d2, d3 };
            Bf[kt][jt] = __builtin_bit_cast(s16x8, u);
        }
    }

    // ---- t = 0 alpha in j-layout: a[r] = alpha[16r + c], replicated x4 ----
    float a[8];
    #pragma unroll
    for (int r = 0; r < 8; ++r)
        a[r] = __expf(startt[16 * r + c] + lpb[16 * r + c]);

    #pragma unroll
    for (int r = 0; r < 8; ++r) xld[16 * r + c] = a[r];

    float S = dpp_sum16(((a[0] + a[1]) + (a[2] + a[3]))
                      + ((a[4] + a[5]) + (a[6] + a[7])));

    int Mexp = 0;                   // exact power-of-2 rescale accumulator

    // emission sets: emA serves odd steps, emB even steps (len >= 256)
    float emA[8], emB[8];
    #pragma unroll
    for (int r = 0; r < 8; ++r) {
        emA[r] = lpb[1 * N_ + 16 * r + c];
        emB[r] = lpb[2 * N_ + 16 * r + c];
    }

    auto step = [&](int t, float (&em)[8]) {
        // consume emissions, then immediately refill the SAME set for t+2
        float eexp[8];
        #pragma unroll
        for (int r = 0; r < 8; ++r) eexp[r] = __expf(em[r]);
        const int rowp = min(t + 2, T_ - 1);        // clamp: always in-bounds
        #pragma unroll
        for (int r = 0; r < 8; ++r) em[r] = lpb[rowp * N_ + 16 * r + c];

        // fragment loads + pack: 2 x ds_read_b128 + 4 x v_perm per kt
        s16x8 Af[4];
        #pragma unroll
        for (int kt = 0; kt < 4; ++kt) {
            const f32x4* ls = (const f32x4*)&xld[32 * kt + 8 * g];
            f32x4 lo = ls[0], hi = ls[1];
            u32x4 u = { pack_bf16(lo[0], lo[1]), pack_bf16(lo[2], lo[3]),
                        pack_bf16(hi[0], hi[1]), pack_bf16(hi[2], hi[3]) };
            Af[kt] = __builtin_bit_cast(s16x8, u);
        }

        // correction y: per jt two independent 2-deep MFMA chains
        float y[8];
        #pragma unroll
        for (int jt = 0; jt < 8; ++jt) {
            f32x4 p = { 0.f, 0.f, 0.f, 0.f };
            f32x4 q = { 0.f, 0.f, 0.f, 0.f };
            p = __builtin_amdgcn_mfma_f32_16x16x32_bf16(Af[0], Bf[0][jt], p, 0, 0, 0);
            q = __builtin_amdgcn_mfma_f32_16x16x32_bf16(Af[2], Bf[2][jt], q, 0, 0, 0);
            p = __builtin_amdgcn_mfma_f32_16x16x32_bf16(Af[1], Bf[1][jt], p, 0, 0, 0);
            q = __builtin_amdgcn_mfma_f32_16x16x32_bf16(Af[3], Bf[3][jt], q, 0, 0, 0);
            y[jt] = p[0] + q[0];
        }

        // a' = S*e + y*e  (S*e computable during the MFMAs)
        #pragma unroll
        for (int r = 0; r < 8; ++r) a[r] = fmaf(y[r], eexp[r], S * eexp[r]);

        if ((t & 3) == 0) {         // exact pow2 rescale, wave-uniform
            float v = readlane_f(a[0], 0);
            unsigned int eb = (__float_as_uint(v) >> 23) & 0xFFu;
            float isc = __uint_as_float((254u - eb) << 23);
            #pragma unroll
            for (int r = 0; r < 8; ++r) a[r] *= isc;
            Mexp += (int)eb - 127;
        }

        #pragma unroll
        for (int r = 0; r < 8; ++r) xld[16 * r + c] = a[r];

        // S for the NEXT step, off the round-trip critical path (DPP only)
        S = dpp_sum16(((a[0] + a[1]) + (a[2] + a[3]))
                    + ((a[4] + a[5]) + (a[6] + a[7])));
    };

    int t = 1;
    while (t + 1 < len) {           // pairs: t (odd, emA) then t+1 (even, emB)
        step(t, emA);
        step(t + 1, emB);
        t += 2;
    }
    if (t < len) step(t, emA);      // tail (t odd -> emA, no rescale there)

    // ---- log Z (values replicated across the 4 lane-groups) ----
    float f = 0.f;
    #pragma unroll
    for (int r = 0; r < 8; ++r) f += a[r] * __expf(endt[16 * r + c]);
    f += __shfl_xor(f, 1); f += __shfl_xor(f, 2);
    f += __shfl_xor(f, 4); f += __shfl_xor(f, 8);
    const float logZ = (float)Mexp * 0.69314718055994531f + __logf(f);

    // ---- path score (gathers) ----
    const int* tg = target + b * T_;
    float acc2 = 0.f;
    for (int t2 = l; t2 < len; t2 += 64) {
        int cc = tg[t2];
        acc2 += lpb[t2 * N_ + cc];
        if (t2 + 1 < len) acc2 += trans[cc * N_ + tg[t2 + 1]];
    }
    #pragma unroll
    for (int off = 32; off > 0; off >>= 1) acc2 += __shfl_xor(acc2, off);

    if (l == 0) out[b] = acc2 + startt[tg[0]] + endt[tg[len - 1]] - logZ;
}

extern "C" void kernel_launch(void* const* d_in, const int* in_sizes, int n_in,
                              void* d_out, int out_size, void* d_ws, size_t ws_size,
                              hipStream_t stream) {
    const float* lp     = (const float*)d_in[0];
    const float* trans  = (const float*)d_in[1];
    const float* st     = (const float*)d_in[2];
    const float* en     = (const float*)d_in[3];
    const int*   target = (const int*)d_in[4];
    const int*   lens   = (const int*)d_in[5];
    float* out = (float*)d_out;

    crf_fused_kernel<<<B_, 64, 0, stream>>>(lp, trans, st, en, target, lens, out);
}

// Round 10
// 290.466 us; speedup vs baseline: 1.4512x; 1.2352x over previous
//
#include <hip/hip_runtime.h>

#define B_ 256
#define T_ 512
#define N_ 128

typedef float  f32x4 __attribute__((ext_vector_type(4)));
typedef short  s16x8 __attribute__((ext_vector_type(8)));
typedef unsigned int u32x4 __attribute__((ext_vector_type(4)));

// round-to-nearest-even f32 -> bf16 (prologue only)
__device__ __forceinline__ unsigned int bf16_rne(float f) {
    unsigned int u = __float_as_uint(f);
    u += 0x7FFFu + ((u >> 16) & 1u);
    return u >> 16;
}
// ONE v_perm_b32: D = (hi.bf16_trunc << 16) | lo.bf16_trunc
__device__ __forceinline__ unsigned int pack_bf16(float lo, float hi) {
    return __builtin_amdgcn_perm(__float_as_uint(hi), __float_as_uint(lo),
                                 0x07060302u);
}
// Barrier draining only LDS (lgkmcnt), NOT vmcnt: emission prefetches stay
// in flight across it.
__device__ __forceinline__ void barrier_lds() {
    asm volatile("s_waitcnt lgkmcnt(0)\n\ts_barrier" ::: "memory");
}

// FOUR waves per chain (256 blocks x 256 threads, 1 wave/SIMD).
// R9 post-mortem: per-SIMD MFMA throughput is ~19 cyc per 16x16x32 (the
// "~5 cyc" figure is per-CU at full occupancy) -> R9's single wave paid
// ~620 cyc/step issuing all 32 MFMAs on one SIMD. Fix: j-split the MFMAs
// across 4 SIMDs, 8 per wave (j-tiles {2w, 2w+1}) -> each wave's y is FINAL
// (it contracts all 128 k itself); the only cross-wave exchange is the
// alpha write-back (one predicated ds_write_b32) + ONE lgkm barrier + the
// broadcast fragment reads (8 x ds_read_b128, conflict-free).
// Same verified Delta-split (R6-R9, absmax 0): e^T = 1 + Delta,
//   alpha_new[j] = e^{E[j]} * ( S + sum_k alpha[k]*Delta[k][j] ),
// S exact f32 (from the same fragment reads, hidden under MFMA issue),
// correction via bf16 MFMA. Rescale scale derived from S (uniform VALU,
// off-path, folded into eexp) - no readlane, exact pow2.
__global__ __launch_bounds__(256, 1) void crf_fused_kernel(
    const float* __restrict__ lp,      // [B,T,N]
    const float* __restrict__ trans,   // [N,N]
    const float* __restrict__ startt,  // [N]
    const float* __restrict__ endt,    // [N]
    const int*   __restrict__ target,  // [B,T]
    const int*   __restrict__ lengths, // [B]
    float*       __restrict__ out)     // [B]
{
    const int b   = blockIdx.x;
    const int tid = threadIdx.x;
    const int w   = tid >> 6;           // wave 0..3 = j-tile pair {2w, 2w+1}
    const int l   = tid & 63;
    const int c   = l & 15;             // column within a 16-wide j-tile
    const int g   = l >> 4;             // k-slot group (0..3)
    const int gp  = g & 1;              // parity: which of the 2 j-tiles

    __shared__ float xld[2][N_];        // [parity][j] alpha (1 KB)
    __shared__ float red[8];

    const float* lpb = lp + (size_t)b * (T_ * N_);
    const int len = lengths[b];         // in [256, 512]

    // ---- Delta fragments for THIS wave's 2 j-tiles: Bf[kt][jtl] ----
    // lane holds Delta[32kt+8g+i][16*(2w+jtl)+c], i paired (even,odd) - byte-
    // identical construction to R6's verified layout, columns restricted.
    s16x8 Bf[4][2];
    #pragma unroll
    for (int kt = 0; kt < 4; ++kt) {
        #pragma unroll
        for (int jtl = 0; jtl < 2; ++jtl) {
            const float* tq = trans + (32 * kt + 8 * g) * N_ + 16 * (2 * w + jtl) + c;
            unsigned d0 = bf16_rne(expm1f(tq[0 * N_])) | (bf16_rne(expm1f(tq[1 * N_])) << 16);
            unsigned d1 = bf16_rne(expm1f(tq[2 * N_])) | (bf16_rne(expm1f(tq[3 * N_])) << 16);
            unsigned d2 = bf16_rne(expm1f(tq[4 * N_])) | (bf16_rne(expm1f(tq[5 * N_])) << 16);
            unsigned d3 = bf16_rne(expm1f(tq[6 * N_])) | (bf16_rne(expm1f(tq[7 * N_])) << 16);
            u32x4 u = { d0, d1, d2, d3 };
            Bf[kt][jtl] = __builtin_bit_cast(s16x8, u);
        }
    }

    // the j this lane writes / tracks emissions for (lanes 32..63 duplicate)
    const int jsel = 32 * w + 16 * gp + c;

    // ---- t = 0 alpha ----
    float a_sel = __expf(startt[jsel] + lpb[jsel]);
    if (l < 32) xld[0][32 * w + l] = a_sel;   // 32 consecutive b32, conflict-free

    int Mexp = 0;                       // exact power-of-2 rescale accumulator

    // emission sets: 1 float per lane; emA serves odd steps, emB even steps
    float emA = lpb[1 * N_ + jsel];
    float emB = lpb[2 * N_ + jsel];

    barrier_lds();                      // xld[0] visible to all waves

    auto step = [&](int t, float& em) {
        const int pr = (t - 1) & 1;     // read parity
        const int pw = t & 1;           // write parity

        // ---- fragment reads (broadcast, conflict-free) + pack + S-partial ----
        s16x8 Af[4];
        f32x4 sv = { 0.f, 0.f, 0.f, 0.f };
        #pragma unroll
        for (int kt = 0; kt < 4; ++kt) {
            const f32x4* ls = (const f32x4*)&xld[pr][32 * kt + 8 * g];
            f32x4 lo = ls[0], hi = ls[1];
            sv += lo + hi;
            u32x4 u = { pack_bf16(lo[0], lo[1]), pack_bf16(lo[2], lo[3]),
                        pack_bf16(hi[0], hi[1]), pack_bf16(hi[2], hi[3]) };
            Af[kt] = __builtin_bit_cast(s16x8, u);
        }
        // S: per-lane 32-value sum + 2 shfls; hidden under MFMA issue
        float S = (sv[0] + sv[1]) + (sv[2] + sv[3]);
        S += __shfl_xor(S, 16);
        S += __shfl_xor(S, 32);

        // ---- emission (1/lane), refill same set for t+2 ----
        float ee = __expf(em);
        em = lpb[(size_t)min(t + 2, T_ - 1) * N_ + jsel];  // clamp: in-bounds

        float e2 = ee;
        if ((t & 3) == 0) {             // pow2 rescale from S: uniform, off-path
            unsigned eb = (__float_as_uint(S) >> 23) & 0xFFu;
            e2 *= __uint_as_float((254u - eb) << 23);
            Mexp += (int)eb - 127;
        }
        const float Se2 = S * e2;

        // ---- 8 MFMAs (this wave's 2 j-tiles), all independent ----
        f32x4 z = { 0.f, 0.f, 0.f, 0.f };
        f32x4 p0 = __builtin_amdgcn_mfma_f32_16x16x32_bf16(Af[0], Bf[0][0], z, 0, 0, 0);
        f32x4 p1 = __builtin_amdgcn_mfma_f32_16x16x32_bf16(Af[0], Bf[0][1], z, 0, 0, 0);
        f32x4 q0 = __builtin_amdgcn_mfma_f32_16x16x32_bf16(Af[1], Bf[1][0], z, 0, 0, 0);
        f32x4 q1 = __builtin_amdgcn_mfma_f32_16x16x32_bf16(Af[1], Bf[1][1], z, 0, 0, 0);
        f32x4 r0 = __builtin_amdgcn_mfma_f32_16x16x32_bf16(Af[2], Bf[2][0], z, 0, 0, 0);
        f32x4 r1 = __builtin_amdgcn_mfma_f32_16x16x32_bf16(Af[2], Bf[2][1], z, 0, 0, 0);
        f32x4 s0 = __builtin_amdgcn_mfma_f32_16x16x32_bf16(Af[3], Bf[3][0], z, 0, 0, 0);
        f32x4 s1 = __builtin_amdgcn_mfma_f32_16x16x32_bf16(Af[3], Bf[3][1], z, 0, 0, 0);
        float y0 = (p0[0] + q0[0]) + (r0[0] + s0[0]);
        float y1 = (p1[0] + q1[0]) + (r1[0] + s1[0]);

        float ysel = gp ? y1 : y0;
        a_sel = fmaf(ysel, e2, Se2);
        if (l < 32) xld[pw][32 * w + l] = a_sel;
        barrier_lds();                  // ONE barrier per step
    };

    int t = 1;
    while (t + 1 < len) {               // pairs: t (odd, emA), t+1 (even, emB)
        step(t, emA);
        step(t + 1, emB);
        t += 2;
    }
    if (t < len) step(t, emA);          // tail

    // ---- logZ partial per wave (g>=2 lanes are duplicates -> zeroed) ----
    {
        float f = (g < 2) ? a_sel * __expf(endt[jsel]) : 0.f;
        #pragma unroll
        for (int off = 32; off > 0; off >>= 1) f += __shfl_xor(f, off);
        if (l == 0) red[w] = f;
    }

    // ---- path score (gathers), all 256 threads ----
    const int* tg = target + b * T_;
    float acc = 0.f;
    for (int t2 = tid; t2 < len; t2 += 256) {
        int cc = tg[t2];
        acc += lpb[t2 * N_ + cc];
        if (t2 + 1 < len) acc += trans[cc * N_ + tg[t2 + 1]];
    }
    #pragma unroll
    for (int off = 32; off > 0; off >>= 1) acc += __shfl_xor(acc, off);
    if (l == 0) red[4 + w] = acc;
    __syncthreads();

    if (tid == 0) {
        float fz = (red[0] + red[1]) + (red[2] + red[3]);
        float sc = (red[4] + red[5]) + (red[6] + red[7]);
        out[b] = sc + startt[tg[0]] + endt[tg[len - 1]]
               - ((float)Mexp * 0.69314718055994531f + __logf(fz));
    }
}

extern "C" void kernel_launch(void* const* d_in, const int* in_sizes, int n_in,
                              void* d_out, int out_size, void* d_ws, size_t ws_size,
                              hipStream_t stream) {
    const float* lp     = (const float*)d_in[0];
    const float* trans  = (const float*)d_in[1];
    const float* st     = (const float*)d_in[2];
    const float* en     = (const float*)d_in[3];
    const int*   target = (const int*)d_in[4];
    const int*   lens   = (const int*)d_in[5];
    float* out = (float*)d_out;

    crf_fused_kernel<<<B_, 256, 0, stream>>>(lp, trans, st, en, target, lens, out);
}

// Round 11
// 231.872 us; speedup vs baseline: 1.8179x; 1.2527x over previous
//
#include <hip/hip_runtime.h>

#define B_ 256
#define T_ 512
#define N_ 128

typedef float  f32x4 __attribute__((ext_vector_type(4)));
typedef short  s16x8 __attribute__((ext_vector_type(8)));
typedef unsigned int u32x4 __attribute__((ext_vector_type(4)));

// round-to-nearest-even f32 -> bf16 (prologue only)
__device__ __forceinline__ unsigned int bf16_rne(float f) {
    unsigned int u = __float_as_uint(f);
    u += 0x7FFFu + ((u >> 16) & 1u);
    return u >> 16;
}
// ONE v_perm_b32: D = (hi.bf16_trunc << 16) | lo.bf16_trunc
__device__ __forceinline__ unsigned int pack_bf16(float lo, float hi) {
    return __builtin_amdgcn_perm(__float_as_uint(hi), __float_as_uint(lo),
                                 0x07060302u);
}
// DPP helpers (compile-time ctrl). R9-verified on HW.
template <int CTRL>
__device__ __forceinline__ float dpp_add(float x) {
    int m = __builtin_amdgcn_update_dpp(0, __float_as_int(x), CTRL, 0xF, 0xF, true);
    return x + __int_as_float(m);
}
__device__ __forceinline__ float dpp_sum16(float s) {
    s = dpp_add<0xB1>(s);      // quad_perm xor1
    s = dpp_add<0x4E>(s);      // quad_perm xor2
    s = dpp_add<0x141>(s);     // row_half_mirror (xor4)
    s = dpp_add<0x140>(s);     // row_mirror (xor8)
    return s;
}
__device__ __forceinline__ float dpp_mov_xor1(float x) {
    int m = __builtin_amdgcn_update_dpp(0, __float_as_int(x), 0xB1, 0xF, 0xF, true);
    return __int_as_float(m);
}
// Barrier draining only LDS (lgkmcnt), NOT vmcnt: emission prefetches stay
// in flight across it.
__device__ __forceinline__ void barrier_lds() {
    asm volatile("s_waitcnt lgkmcnt(0)\n\ts_barrier" ::: "memory");
}

// FOUR waves per chain (256 blocks x 256 threads, 1 wave/SIMD).
// Verified Delta-split (R6-R10, absmax 0): e^T = 1 + Delta,
//   alpha_new[j] = e^{E[j]} * ( S + sum_k alpha[k]*Delta[k][j] ),
// correction via bf16 MFMA, wave w owns j-tiles {2w,2w+1} (8 MFMA/wave/step).
// R11 (vs R10, which measured VALU issue 225 cyc/step as the top reducible):
//  - alpha is stored in LDS ALREADY bf16-PACKED: each lane packs (own, c^1
//    neighbor) via 1 DPP mov + 1 v_perm; even lanes of l<32 write one b32.
//    Fragment loads become 4 x ds_read_b128 of ready A-fragments: deletes
//    4 reads + 16 packs/step. MFMA inputs bitwise-identical to R10 (same
//    v_perm truncation).
//  - S via write-side recursion: per-16-lane DPP tree (4 VALU adds), lanes
//    0/16 write group partials; next step reads 8 floats (2 x b128) + adds.
//    Deletes the 32-add redundant sum + 2 shfl_xor, and S is ready right
//    after the barrier (Se2 computable during the MFMAs).
__global__ __launch_bounds__(256, 1) void crf_fused_kernel(
    const float* __restrict__ lp,      // [B,T,N]
    const float* __restrict__ trans,   // [N,N]
    const float* __restrict__ startt,  // [N]
    const float* __restrict__ endt,    // [N]
    const int*   __restrict__ target,  // [B,T]
    const int*   __restrict__ lengths, // [B]
    float*       __restrict__ out)     // [B]
{
    const int b   = blockIdx.x;
    const int tid = threadIdx.x;
    const int w   = tid >> 6;           // wave 0..3 = j-tile pair {2w, 2w+1}
    const int l   = tid & 63;
    const int c   = l & 15;             // column within a 16-wide j-tile
    const int g   = l >> 4;             // k-slot group (0..3)
    const int gp  = g & 1;              // which of the wave's 2 j-tiles

    __shared__ alignas(16) unsigned int xbf[2][64];  // packed bf16 alpha [parity][u32]
    __shared__ alignas(16) float P2[2][8];           // per-16-group partial sums
    __shared__ float red[8];

    const float* lpb = lp + (size_t)b * (T_ * N_);
    const int len = lengths[b];         // in [256, 512]

    // ---- Delta fragments for THIS wave's 2 j-tiles (R10-identical) ----
    s16x8 Bf[4][2];
    #pragma unroll
    for (int kt = 0; kt < 4; ++kt) {
        #pragma unroll
        for (int jtl = 0; jtl < 2; ++jtl) {
            const float* tq = trans + (32 * kt + 8 * g) * N_ + 16 * (2 * w + jtl) + c;
            unsigned d0 = bf16_rne(expm1f(tq[0 * N_])) | (bf16_rne(expm1f(tq[1 * N_])) << 16);
            unsigned d1 = bf16_rne(expm1f(tq[2 * N_])) | (bf16_rne(expm1f(tq[3 * N_])) << 16);
            unsigned d2 = bf16_rne(expm1f(tq[4 * N_])) | (bf16_rne(expm1f(tq[5 * N_])) << 16);
            unsigned d3 = bf16_rne(expm1f(tq[6 * N_])) | (bf16_rne(expm1f(tq[7 * N_])) << 16);
            u32x4 u = { d0, d1, d2, d3 };
            Bf[kt][jtl] = __builtin_bit_cast(s16x8, u);
        }
    }

    // the j this lane owns (lanes 32..63 duplicate lanes 0..31)
    const int jsel = 32 * w + 16 * gp + c;

    float a_sel = __expf(startt[jsel] + lpb[jsel]);

    // write-side finish: pack alpha (bf16 pairs) + S group-partials
    auto finish = [&](int par, float av) {
        float nb    = dpp_mov_xor1(av);          // neighbor a' (k odd)
        unsigned pk = pack_bf16(av, nb);         // even lane: own->lo, odd->hi
        if (l < 32 && !(l & 1))
            xbf[par][16 * w + 8 * gp + (c >> 1)] = pk;
        float s16 = dpp_sum16(av);               // sum of this 16-group's j's
        if (c == 0 && g < 2)                     // lanes 0 and 16
            P2[par][2 * w + g] = s16;
    };
    finish(0, a_sel);

    int Mexp = 0;                       // exact power-of-2 rescale accumulator

    // emission regs: emA serves odd steps, emB even steps (len >= 256)
    float emA = lpb[1 * N_ + jsel];
    float emB = lpb[2 * N_ + jsel];

    barrier_lds();

    auto step = [&](int t, float& em) {
        const int pr = (t - 1) & 1;     // read parity
        const int pw = t & 1;           // write parity

        // ---- S: 2 x b128 of group partials + 7 adds (ready immediately) ----
        f32x4 pa = *(const f32x4*)&P2[pr][0];
        f32x4 pb = *(const f32x4*)&P2[pr][4];
        f32x4 ps = pa + pb;
        float S = (ps[0] + ps[1]) + (ps[2] + ps[3]);

        // ---- A fragments: 4 x ds_read_b128, already bf16-packed ----
        s16x8 Af[4];
        #pragma unroll
        for (int kt = 0; kt < 4; ++kt)
            Af[kt] = *(const s16x8*)&xbf[pr][16 * kt + 4 * g];

        // ---- emission (1/lane), refill same set for t+2 ----
        float ee = __expf(em);
        em = lpb[(size_t)min(t + 2, T_ - 1) * N_ + jsel];  // clamp: in-bounds

        float e2 = ee;
        if ((t & 3) == 0) {             // pow2 rescale from S: uniform, off-path
            unsigned eb = (__float_as_uint(S) >> 23) & 0xFFu;
            e2 *= __uint_as_float((254u - eb) << 23);
            Mexp += (int)eb - 127;
        }
        const float Se2 = S * e2;

        // ---- 8 MFMAs: two independent 2-deep chains per j-tile ----
        f32x4 z = { 0.f, 0.f, 0.f, 0.f };
        f32x4 pA = __builtin_amdgcn_mfma_f32_16x16x32_bf16(Af[0], Bf[0][0], z, 0, 0, 0);
        f32x4 qA = __builtin_amdgcn_mfma_f32_16x16x32_bf16(Af[2], Bf[2][0], z, 0, 0, 0);
        f32x4 pB = __builtin_amdgcn_mfma_f32_16x16x32_bf16(Af[0], Bf[0][1], z, 0, 0, 0);
        f32x4 qB = __builtin_amdgcn_mfma_f32_16x16x32_bf16(Af[2], Bf[2][1], z, 0, 0, 0);
        pA = __builtin_amdgcn_mfma_f32_16x16x32_bf16(Af[1], Bf[1][0], pA, 0, 0, 0);
        qA = __builtin_amdgcn_mfma_f32_16x16x32_bf16(Af[3], Bf[3][0], qA, 0, 0, 0);
        pB = __builtin_amdgcn_mfma_f32_16x16x32_bf16(Af[1], Bf[1][1], pB, 0, 0, 0);
        qB = __builtin_amdgcn_mfma_f32_16x16x32_bf16(Af[3], Bf[3][1], qB, 0, 0, 0);
        float y0 = pA[0] + qA[0];
        float y1 = pB[0] + qB[0];

        float ysel = gp ? y1 : y0;
        a_sel = fmaf(ysel, e2, Se2);
        finish(pw, a_sel);
        barrier_lds();                  // ONE barrier per step
    };

    int t = 1;
    while (t + 1 < len) {               // pairs: t (odd, emA), t+1 (even, emB)
        step(t, emA);
        step(t + 1, emB);
        t += 2;
    }
    if (t < len) step(t, emA);          // tail

    // ---- logZ partial per wave (g>=2 lanes are duplicates -> zeroed) ----
    {
        float f = (g < 2) ? a_sel * __expf(endt[jsel]) : 0.f;
        #pragma unroll
        for (int off = 32; off > 0; off >>= 1) f += __shfl_xor(f, off);
        if (l == 0) red[w] = f;
    }

    // ---- path score (gathers), all 256 threads ----
    const int* tg = target + b * T_;
    float acc = 0.f;
    for (int t2 = tid; t2 < len; t2 += 256) {
        int cc = tg[t2];
        acc += lpb[t2 * N_ + cc];
        if (t2 + 1 < len) acc += trans[cc * N_ + tg[t2 + 1]];
    }
    #pragma unroll
    for (int off = 32; off > 0; off >>= 1) acc += __shfl_xor(acc, off);
    if (l == 0) red[4 + w] = acc;
    __syncthreads();

    if (tid == 0) {
        float fz = (red[0] + red[1]) + (red[2] + red[3]);
        float sc = (red[4] + red[5]) + (red[6] + red[7]);
        out[b] = sc + startt[tg[0]] + endt[tg[len - 1]]
               - ((float)Mexp * 0.69314718055994531f + __logf(fz));
    }
}

extern "C" void kernel_launch(void* const* d_in, const int* in_sizes, int n_in,
                              void* d_out, int out_size, void* d_ws, size_t ws_size,
                              hipStream_t stream) {
    const float* lp     = (const float*)d_in[0];
    const float* trans  = (const float*)d_in[1];
    const float* st     = (const float*)d_in[2];
    const float* en     = (const float*)d_in[3];
    const int*   target = (const int*)d_in[4];
    const int*   lens   = (const int*)d_in[5];
    float* out = (float*)d_out;

    crf_fused_kernel<<<B_, 256, 0, stream>>>(lp, trans, st, en, target, lens, out);
}

// Round 12
// 223.375 us; speedup vs baseline: 1.8870x; 1.0380x over previous
//
#include <hip/hip_runtime.h>

#define B_ 256
#define T_ 512
#define N_ 128

typedef float  f32x4 __attribute__((ext_vector_type(4)));
typedef short  s16x8 __attribute__((ext_vector_type(8)));
typedef unsigned int u32x4 __attribute__((ext_vector_type(4)));

// round-to-nearest-even f32 -> bf16 (prologue only)
__device__ __forceinline__ unsigned int bf16_rne(float f) {
    unsigned int u = __float_as_uint(f);
    u += 0x7FFFu + ((u >> 16) & 1u);
    return u >> 16;
}
// ONE v_perm_b32: D = (hi.bf16_trunc << 16) | lo.bf16_trunc
__device__ __forceinline__ unsigned int pack_bf16(float lo, float hi) {
    return __builtin_amdgcn_perm(__float_as_uint(hi), __float_as_uint(lo),
                                 0x07060302u);
}
// DPP helpers (compile-time ctrl).
template <int CTRL>
__device__ __forceinline__ float dpp_add(float x) {
    int m = __builtin_amdgcn_update_dpp(0, __float_as_int(x), CTRL, 0xF, 0xF, true);
    return x + __int_as_float(m);
}
__device__ __forceinline__ float dpp_sum16(float s) {
    s = dpp_add<0xB1>(s);      // quad_perm xor1
    s = dpp_add<0x4E>(s);      // quad_perm xor2
    s = dpp_add<0x141>(s);     // row_half_mirror (xor4)
    s = dpp_add<0x140>(s);     // row_mirror (xor8)
    return s;
}
__device__ __forceinline__ float dpp_mov_xor1(float x) {
    int m = __builtin_amdgcn_update_dpp(0, __float_as_int(x), 0xB1, 0xF, 0xF, true);
    return __int_as_float(m);
}
// Barrier draining only LDS (lgkmcnt), NOT vmcnt: emission prefetches stay
// in flight across it.
__device__ __forceinline__ void barrier_lds() {
    asm volatile("s_waitcnt lgkmcnt(0)\n\ts_barrier" ::: "memory");
}

// FOUR waves per chain (256 blocks x 256 threads, 1 wave/SIMD).
// Verified Delta-split (R6-R11, absmax 0): e^T = 1 + Delta,
//   alpha_new[j] = e^{E[j]} * ( S + sum_k alpha[k]*Delta[k][j] ),
// correction via bf16 MFMA, wave w owns j-tiles {2w,2w+1} (8 MFMA/wave/step),
// alpha stored in LDS bf16-packed, S via write-side DPP recursion (R11).
// R12 (vs R11; calibration: step = F(~620 fixed) + VALU_issue + MFMA_issue):
//  - 4-step unrolled body, STATIC parities and STATIC rescale slot (t=1 mod 4
//    at loop head -> rescale exactly in slot 4): no per-step branch, long
//    straight-line scheduling region.
//  - emission distance-4: all four expf at body top consume 4-step-old loads,
//    then all four refills issue. Any vmcnt(N) the compiler places now waits
//    only on ~3000-cycle-old loads -> provably no vmcnt stall.
//  - Af reads issued before S reads (first consumer first).
__global__ __launch_bounds__(256, 1) void crf_fused_kernel(
    const float* __restrict__ lp,      // [B,T,N]
    const float* __restrict__ trans,   // [N,N]
    const float* __restrict__ startt,  // [N]
    const float* __restrict__ endt,    // [N]
    const int*   __restrict__ target,  // [B,T]
    const int*   __restrict__ lengths, // [B]
    float*       __restrict__ out)     // [B]
{
    const int b   = blockIdx.x;
    const int tid = threadIdx.x;
    const int w   = tid >> 6;           // wave 0..3 = j-tile pair {2w, 2w+1}
    const int l   = tid & 63;
    const int c   = l & 15;             // column within a 16-wide j-tile
    const int g   = l >> 4;             // k-slot group (0..3)
    const int gp  = g & 1;              // which of the wave's 2 j-tiles

    __shared__ alignas(16) unsigned int xbf[2][64];  // packed bf16 alpha
    __shared__ alignas(16) float P2[2][8];           // per-16-group partials
    __shared__ float red[8];

    const float* lpb = lp + (size_t)b * (T_ * N_);
    const int len = lengths[b];         // in [256, 512]

    // ---- Delta fragments for THIS wave's 2 j-tiles (R10/R11-identical) ----
    s16x8 Bf[4][2];
    #pragma unroll
    for (int kt = 0; kt < 4; ++kt) {
        #pragma unroll
        for (int jtl = 0; jtl < 2; ++jtl) {
            const float* tq = trans + (32 * kt + 8 * g) * N_ + 16 * (2 * w + jtl) + c;
            unsigned d0 = bf16_rne(expm1f(tq[0 * N_])) | (bf16_rne(expm1f(tq[1 * N_])) << 16);
            unsigned d1 = bf16_rne(expm1f(tq[2 * N_])) | (bf16_rne(expm1f(tq[3 * N_])) << 16);
            unsigned d2 = bf16_rne(expm1f(tq[4 * N_])) | (bf16_rne(expm1f(tq[5 * N_])) << 16);
            unsigned d3 = bf16_rne(expm1f(tq[6 * N_])) | (bf16_rne(expm1f(tq[7 * N_])) << 16);
            u32x4 u = { d0, d1, d2, d3 };
            Bf[kt][jtl] = __builtin_bit_cast(s16x8, u);
        }
    }

    // the j this lane owns (lanes 32..63 duplicate lanes 0..31)
    const int jsel = 32 * w + 16 * gp + c;

    float a_sel = __expf(startt[jsel] + lpb[jsel]);

    // write-side finish: pack alpha (bf16 pairs) + S group-partials
    auto finish = [&](int par, float av) {
        float nb    = dpp_mov_xor1(av);
        unsigned pk = pack_bf16(av, nb);
        if (l < 32 && !(l & 1))
            xbf[par][16 * w + 8 * gp + (c >> 1)] = pk;
        float s16v = dpp_sum16(av);
        if (c == 0 && g < 2)                     // lanes 0 and 16
            P2[par][2 * w + g] = s16v;
    };
    finish(0, a_sel);

    int Mexp = 0;                       // exact power-of-2 rescale accumulator

    // emission regs, distance 4: slot s serves steps t with (t-1)&3 == s
    const float* emp = lpb + jsel;
    float em0 = emp[1 * N_], em1 = emp[2 * N_];
    float em2 = emp[3 * N_], em3 = emp[4 * N_];   // rows 1..4 valid (len>=256)

    barrier_lds();

    // one step; pr/resc become literals at every call site -> fully static
    auto step = [&](float ee, bool resc, int pr) {
        const int pw = pr ^ 1;

        // ---- A fragments first (first consumer), then S partials ----
        s16x8 Af0 = *(const s16x8*)&xbf[pr][ 0 + 4 * g];
        s16x8 Af1 = *(const s16x8*)&xbf[pr][16 + 4 * g];
        s16x8 Af2 = *(const s16x8*)&xbf[pr][32 + 4 * g];
        s16x8 Af3 = *(const s16x8*)&xbf[pr][48 + 4 * g];
        f32x4 pa = *(const f32x4*)&P2[pr][0];
        f32x4 pb = *(const f32x4*)&P2[pr][4];
        f32x4 ps = pa + pb;
        float S = (ps[0] + ps[1]) + (ps[2] + ps[3]);

        float e2 = ee;
        if (resc) {                     // static slot: no runtime branch
            unsigned eb = (__float_as_uint(S) >> 23) & 0xFFu;
            e2 *= __uint_as_float((254u - eb) << 23);
            Mexp += (int)eb - 127;
        }
        const float Se2 = S * e2;

        // ---- 8 MFMAs: two independent 2-deep chains per j-tile ----
        f32x4 z = { 0.f, 0.f, 0.f, 0.f };
        f32x4 pA = __builtin_amdgcn_mfma_f32_16x16x32_bf16(Af0, Bf[0][0], z, 0, 0, 0);
        f32x4 qA = __builtin_amdgcn_mfma_f32_16x16x32_bf16(Af2, Bf[2][0], z, 0, 0, 0);
        f32x4 pB = __builtin_amdgcn_mfma_f32_16x16x32_bf16(Af0, Bf[0][1], z, 0, 0, 0);
        f32x4 qB = __builtin_amdgcn_mfma_f32_16x16x32_bf16(Af2, Bf[2][1], z, 0, 0, 0);
        pA = __builtin_amdgcn_mfma_f32_16x16x32_bf16(Af1, Bf[1][0], pA, 0, 0, 0);
        qA = __builtin_amdgcn_mfma_f32_16x16x32_bf16(Af3, Bf[3][0], qA, 0, 0, 0);
        pB = __builtin_amdgcn_mfma_f32_16x16x32_bf16(Af1, Bf[1][1], pB, 0, 0, 0);
        qB = __builtin_amdgcn_mfma_f32_16x16x32_bf16(Af3, Bf[3][1], qB, 0, 0, 0);
        float y0 = pA[0] + qA[0];
        float y1 = pB[0] + qB[0];

        a_sel = fmaf(gp ? y1 : y0, e2, Se2);
        finish(pw, a_sel);
        barrier_lds();                  // ONE barrier per step
    };

    int t = 1;                          // invariant: t = 1 (mod 4) at loop head
    while (t + 3 < len) {
        // exps from 4-step-old loads; THEN refill (WAR on regs, no wait)
        float ee0 = __expf(em0), ee1 = __expf(em1);
        float ee2 = __expf(em2), ee3 = __expf(em3);
        em0 = emp[(size_t)min(t + 4, T_ - 1) * N_];
        em1 = emp[(size_t)min(t + 5, T_ - 1) * N_];
        em2 = emp[(size_t)min(t + 6, T_ - 1) * N_];
        em3 = emp[(size_t)min(t + 7, T_ - 1) * N_];

        step(ee0, false, 0);            // t   : pr=0
        step(ee1, false, 1);            // t+1 : pr=1
        step(ee2, false, 0);            // t+2 : pr=0
        step(ee3, true,  1);            // t+3 = 0 mod 4 : rescale
        t += 4;
    }
    // tail (<=3 steps, t = 1,2,3 mod 4 -> never a rescale slot)
    if (t < len) { step(__expf(em0), false, 0); ++t; }
    if (t < len) { step(__expf(em1), false, 1); ++t; }
    if (t < len) { step(__expf(em2), false, 0); ++t; }

    // ---- logZ partial per wave (g>=2 lanes are duplicates -> zeroed) ----
    {
        float f = (g < 2) ? a_sel * __expf(endt[jsel]) : 0.f;
        #pragma unroll
        for (int off = 32; off > 0; off >>= 1) f += __shfl_xor(f, off);
        if (l == 0) red[w] = f;
    }

    // ---- path score (gathers), all 256 threads ----
    const int* tg = target + b * T_;
    float acc = 0.f;
    for (int t2 = tid; t2 < len; t2 += 256) {
        int cc = tg[t2];
        acc += lpb[t2 * N_ + cc];
        if (t2 + 1 < len) acc += trans[cc * N_ + tg[t2 + 1]];
    }
    #pragma unroll
    for (int off = 32; off > 0; off >>= 1) acc += __shfl_xor(acc, off);
    if (l == 0) red[4 + w] = acc;
    __syncthreads();

    if (tid == 0) {
        float fz = (red[0] + red[1]) + (red[2] + red[3]);
        float sc = (red[4] + red[5]) + (red[6] + red[7]);
        out[b] = sc + startt[tg[0]] + endt[tg[len - 1]]
               - ((float)Mexp * 0.69314718055994531f + __logf(fz));
    }
}

extern "C" void kernel_launch(void* const* d_in, const int* in_sizes, int n_in,
                              void* d_out, int out_size, void* d_ws, size_t ws_size,
                              hipStream_t stream) {
    const float* lp     = (const float*)d_in[0];
    const float* trans  = (const float*)d_in[1];
    const float* st     = (const float*)d_in[2];
    const float* en     = (const float*)d_in[3];
    const int*   target = (const int*)d_in[4];
    const int*   lens   = (const int*)d_in[5];
    float* out = (float*)d_out;

    crf_fused_kernel<<<B_, 256, 0, stream>>>(lp, trans, st, en, target, lens, out);
}